// Round 1
// baseline (1806.974 us; speedup 1.0000x reference)
//
#include <hip/hip_runtime.h>
#include <hip/hip_bf16.h>

// Problem constants
#define B_ 2
#define S_ 2048
#define D_ 1024
#define H_ 16
#define P_ 2048
#define T_ 4096   // P_ + S_
#define DEPTH_ 64

// =====================================================================
// GEMM: C[4096, NCOLS] = A[4096,1024] @ W[1024,NCOLS] + bias
// 128x128 tile, K-step 16, 256 threads, 8x8 micro-tile per thread.
// MODE 0: QKV epilogue (scatter q -> ws, k/v -> present)
// MODE 1: plain epilogue (output projection)
// =====================================================================
template<int MODE, int NCOLS>
__global__ __launch_bounds__(256)
void gemm_kernel(const float* __restrict__ A, const float* __restrict__ W,
                 const float* __restrict__ bias,
                 float* __restrict__ out_q, float* __restrict__ out_present,
                 float* __restrict__ out_plain)
{
    __shared__ float As[16][132];   // [k][m], padded
    __shared__ float Bs[16][132];   // [k][n], padded

    const int tid  = threadIdx.x;
    const int ty   = tid >> 4;       // 0..15 -> rows ty*8..ty*8+7
    const int tx   = tid & 15;       // 0..15 -> cols tx*8..tx*8+7
    const int row0 = blockIdx.y * 128;
    const int col0 = blockIdx.x * 128;

    float acc[8][8];
    #pragma unroll
    for (int i = 0; i < 8; ++i)
        #pragma unroll
        for (int j = 0; j < 8; ++j) acc[i][j] = 0.f;

    for (int k0 = 0; k0 < 1024; k0 += 16) {
        // stage A tile transposed: As[k][m]  (128 rows x 16 k = 512 float4)
        // stage B tile direct:     Bs[k][n]  (16 k x 128 cols = 512 float4)
        #pragma unroll
        for (int rep = 0; rep < 2; ++rep) {
            const int idx = rep * 256 + tid;        // 0..511
            const int r  = idx >> 2, c  = idx & 3;  // A: row r, k-group c
            float4 av = *(const float4*)&A[(size_t)(row0 + r) * 1024 + k0 + c * 4];
            As[c*4+0][r] = av.x; As[c*4+1][r] = av.y;
            As[c*4+2][r] = av.z; As[c*4+3][r] = av.w;
            const int kk = idx >> 5, cc = idx & 31; // B: k row kk, col-group cc
            float4 bv = *(const float4*)&W[(size_t)(k0 + kk) * NCOLS + col0 + cc * 4];
            *(float4*)&Bs[kk][cc*4] = bv;
        }
        __syncthreads();

        #pragma unroll
        for (int kk = 0; kk < 16; ++kk) {
            float4 a0 = *(const float4*)&As[kk][ty*8];
            float4 a1 = *(const float4*)&As[kk][ty*8+4];
            float4 b0 = *(const float4*)&Bs[kk][tx*8];
            float4 b1 = *(const float4*)&Bs[kk][tx*8+4];
            float a[8]  = {a0.x,a0.y,a0.z,a0.w,a1.x,a1.y,a1.z,a1.w};
            float bb[8] = {b0.x,b0.y,b0.z,b0.w,b1.x,b1.y,b1.z,b1.w};
            #pragma unroll
            for (int i = 0; i < 8; ++i)
                #pragma unroll
                for (int j = 0; j < 8; ++j)
                    acc[i][j] = fmaf(a[i], bb[j], acc[i][j]);
        }
        __syncthreads();
    }

    // epilogue
    #pragma unroll
    for (int i = 0; i < 8; ++i) {
        const int rm = row0 + ty * 8 + i;
        const int b  = rm >> 11;         // /2048
        const int s  = rm & 2047;
        #pragma unroll
        for (int jg = 0; jg < 2; ++jg) {
            const int e0 = col0 + tx * 8 + jg * 4;
            float4 v;
            v.x = acc[i][jg*4+0] + bias[e0+0];
            v.y = acc[i][jg*4+1] + bias[e0+1];
            v.z = acc[i][jg*4+2] + bias[e0+2];
            v.w = acc[i][jg*4+3] + bias[e0+3];
            if (MODE == 0) {
                const int which = e0 >> 10;      // 0=q 1=k 2=v
                const int f = e0 & 1023;
                const int h = f >> 6, d = f & 63;
                if (which == 0) {
                    // ws q: [B,H,S,64]
                    *(float4*)&out_q[(size_t)(((b*16 + h) * 2048 + s) << 6) + d] = v;
                } else {
                    const int kv = which - 1;
                    // present: [B,2,H,4096,64], new rows at P_+s
                    *(float4*)&out_present[((((size_t)(b*2 + kv)*16 + h) * 4096 + 2048 + s) << 6) + d] = v;
                }
            } else {
                *(float4*)&out_plain[(size_t)rm * 1024 + e0] = v;
            }
        }
    }
}

// =====================================================================
// past_layer [B,2,H,P,64] -> present[b,kv,h,0:P,:]
// 64 contiguous chunks of P*64 floats each; dest chunk stride T*64.
// =====================================================================
__global__ __launch_bounds__(256)
void copy_past_kernel(const float4* __restrict__ past, float4* __restrict__ present4)
{
    const int idx = blockIdx.x * 256 + threadIdx.x;   // 0 .. 2,097,151
    if (idx >= (B_*2*H_*P_*DEPTH_)/4) return;
    const int c = idx >> 15;          // / (P_*64/4 = 32768)
    const int r = idx & 32767;
    present4[(size_t)c * (T_*DEPTH_/4) + r] = past[idx];
}

// =====================================================================
// Flash attention (fp32): one block = 64 q rows of one (b,h).
// K/V tiles of 64 keys staged in LDS; online softmax; causal mask only
// on the diagonal tile (q row r is at absolute pos P_+q0+r).
// =====================================================================
__global__ __launch_bounds__(256)
void attn_kernel(const float* __restrict__ qin,      // [B,H,S,64]
                 const float* __restrict__ present,  // [B,2,H,T,64]
                 float* __restrict__ merged)         // [B,S,D]
{
    __shared__ float Qs[64][68];    // [d][r]
    __shared__ float KPs[64][68];   // K: [d][j]; reused as P: [r][j]
    __shared__ float Vs[64][68];    // [j][d]

    const int tid = threadIdx.x;
    const int ty  = tid >> 4;   // rows ty*4 .. +3
    const int tx  = tid & 15;   // cols tx*4 .. +3
    const int q0  = blockIdx.x * 64;
    const int bh  = blockIdx.y;
    const int b   = bh >> 4, h = bh & 15;

    const float* Kbase = present + ((size_t)(b*2 + 0)*16 + h) * (T_*DEPTH_);
    const float* Vbase = present + ((size_t)(b*2 + 1)*16 + h) * (T_*DEPTH_);
    const float* Qbase = qin + ((size_t)bh * 2048 + q0) * 64;

    // load Q tile transposed: Qs[d][r]
    #pragma unroll
    for (int rep = 0; rep < 4; ++rep) {
        const int idx = rep * 256 + tid;
        const int r = idx >> 4, c = idx & 15;
        float4 v = *(const float4*)&Qbase[r * 64 + c * 4];
        Qs[c*4+0][r] = v.x; Qs[c*4+1][r] = v.y;
        Qs[c*4+2][r] = v.z; Qs[c*4+3][r] = v.w;
    }
    // (first in-loop __syncthreads covers Qs before first use)

    float m_r[4], l_r[4], ctx[4][4];
    #pragma unroll
    for (int i = 0; i < 4; ++i) {
        m_r[i] = -3.0e38f; l_r[i] = 0.f;
        #pragma unroll
        for (int j = 0; j < 4; ++j) ctx[i][j] = 0.f;
    }

    const int nt = (2048 + q0) / 64 + 1;   // tiles needed (last = diagonal)
    for (int t = 0; t < nt; ++t) {
        const int t0 = t * 64;
        // stage K transposed ([d][j]) and V direct ([j][d])
        #pragma unroll
        for (int rep = 0; rep < 4; ++rep) {
            const int idx = rep * 256 + tid;
            const int r = idx >> 4, c = idx & 15;
            float4 k4 = *(const float4*)&Kbase[(size_t)(t0 + r) * 64 + c * 4];
            KPs[c*4+0][r] = k4.x; KPs[c*4+1][r] = k4.y;
            KPs[c*4+2][r] = k4.z; KPs[c*4+3][r] = k4.w;
            float4 v4 = *(const float4*)&Vbase[(size_t)(t0 + r) * 64 + c * 4];
            *(float4*)&Vs[r][c*4] = v4;
        }
        __syncthreads();

        // scores: sc[i][j] = sum_d Q[r][d]*K[j][d]
        float sc[4][4];
        #pragma unroll
        for (int i = 0; i < 4; ++i)
            #pragma unroll
            for (int j = 0; j < 4; ++j) sc[i][j] = 0.f;
        #pragma unroll
        for (int d = 0; d < 64; ++d) {
            float4 q4 = *(const float4*)&Qs[d][ty*4];
            float4 k4 = *(const float4*)&KPs[d][tx*4];
            float qa[4] = {q4.x,q4.y,q4.z,q4.w};
            float ka[4] = {k4.x,k4.y,k4.z,k4.w};
            #pragma unroll
            for (int i = 0; i < 4; ++i)
                #pragma unroll
                for (int j = 0; j < 4; ++j)
                    sc[i][j] = fmaf(qa[i], ka[j], sc[i][j]);
        }

        // scale + causal mask (diagonal tile only: key j allowed iff j <= r)
        const bool diag = (t == nt - 1);
        #pragma unroll
        for (int i = 0; i < 4; ++i)
            #pragma unroll
            for (int j = 0; j < 4; ++j) {
                sc[i][j] *= 0.125f;
                if (diag && (tx*4 + j > ty*4 + i)) sc[i][j] = -1e9f;
            }

        // online softmax per row (row owned by the 16 lanes sharing ty)
        #pragma unroll
        for (int i = 0; i < 4; ++i) {
            float mx = fmaxf(fmaxf(sc[i][0], sc[i][1]), fmaxf(sc[i][2], sc[i][3]));
            mx = fmaxf(mx, __shfl_xor(mx, 1));
            mx = fmaxf(mx, __shfl_xor(mx, 2));
            mx = fmaxf(mx, __shfl_xor(mx, 4));
            mx = fmaxf(mx, __shfl_xor(mx, 8));
            const float mnew = fmaxf(m_r[i], mx);
            const float corr = __expf(m_r[i] - mnew);
            float rs = 0.f;
            #pragma unroll
            for (int j = 0; j < 4; ++j) {
                const float p = __expf(sc[i][j] - mnew);
                sc[i][j] = p; rs += p;
            }
            rs += __shfl_xor(rs, 1);
            rs += __shfl_xor(rs, 2);
            rs += __shfl_xor(rs, 4);
            rs += __shfl_xor(rs, 8);
            l_r[i] = l_r[i] * corr + rs;
            m_r[i] = mnew;
            #pragma unroll
            for (int j = 0; j < 4; ++j) ctx[i][j] *= corr;
        }

        __syncthreads();  // everyone done reading KPs (K) before P overwrite
        #pragma unroll
        for (int i = 0; i < 4; ++i) {
            float4 p4 = make_float4(sc[i][0], sc[i][1], sc[i][2], sc[i][3]);
            *(float4*)&KPs[ty*4 + i][tx*4] = p4;
        }
        __syncthreads();

        // PV: ctx[i][j] += sum_jj P[r][jj] * V[jj][tx*4+j]
        #pragma unroll
        for (int jj = 0; jj < 16; ++jj) {
            float4 pr0 = *(const float4*)&KPs[ty*4+0][jj*4];
            float4 pr1 = *(const float4*)&KPs[ty*4+1][jj*4];
            float4 pr2 = *(const float4*)&KPs[ty*4+2][jj*4];
            float4 pr3 = *(const float4*)&KPs[ty*4+3][jj*4];
            float4 w0 = *(const float4*)&Vs[jj*4+0][tx*4];
            float4 w1 = *(const float4*)&Vs[jj*4+1][tx*4];
            float4 w2 = *(const float4*)&Vs[jj*4+2][tx*4];
            float4 w3 = *(const float4*)&Vs[jj*4+3][tx*4];
            float pr[4][4] = {{pr0.x,pr0.y,pr0.z,pr0.w},
                              {pr1.x,pr1.y,pr1.z,pr1.w},
                              {pr2.x,pr2.y,pr2.z,pr2.w},
                              {pr3.x,pr3.y,pr3.z,pr3.w}};
            float vv[4][4] = {{w0.x,w0.y,w0.z,w0.w},
                              {w1.x,w1.y,w1.z,w1.w},
                              {w2.x,w2.y,w2.z,w2.w},
                              {w3.x,w3.y,w3.z,w3.w}};
            #pragma unroll
            for (int i = 0; i < 4; ++i)
                #pragma unroll
                for (int jp = 0; jp < 4; ++jp)
                    #pragma unroll
                    for (int j = 0; j < 4; ++j)
                        ctx[i][j] = fmaf(pr[i][jp], vv[jp][j], ctx[i][j]);
        }
        __syncthreads();  // before next tile overwrites KPs/Vs
    }

    // write merged [b, s, h*64 + d]
    #pragma unroll
    for (int i = 0; i < 4; ++i) {
        const int r = ty*4 + i;
        const float inv = 1.f / l_r[i];
        float4 o = make_float4(ctx[i][0]*inv, ctx[i][1]*inv, ctx[i][2]*inv, ctx[i][3]*inv);
        *(float4*)&merged[((size_t)b * 2048 + q0 + r) * 1024 + h*64 + tx*4] = o;
    }
}

// =====================================================================
extern "C" void kernel_launch(void* const* d_in, const int* in_sizes, int n_in,
                              void* d_out, int out_size, void* d_ws, size_t ws_size,
                              hipStream_t stream)
{
    const float* x      = (const float*)d_in[0];
    // d_in[1] = mask: causal structure computed analytically, never read
    const float* past   = (const float*)d_in[2];
    const float* w_attn = (const float*)d_in[3];
    const float* b_attn = (const float*)d_in[4];
    const float* w_proj = (const float*)d_in[5];
    const float* b_proj = (const float*)d_in[6];

    float* out     = (float*)d_out;                    // [B,S,D]
    float* present = out + (size_t)B_ * S_ * D_;       // [B,2,H,T,64]
    float* q_ws    = (float*)d_ws;                     // [B,H,S,64]
    float* merged  = q_ws + (size_t)B_ * H_ * S_ * DEPTH_;  // [B,S,D]

    // 1) QKV projection; scatter q->ws, k/v->present (new rows)
    gemm_kernel<0, 3072><<<dim3(24, 32), 256, 0, stream>>>(
        x, w_attn, b_attn, q_ws, present, nullptr);

    // 2) past -> present (rows 0..P-1)
    copy_past_kernel<<<dim3((B_*2*H_*P_*DEPTH_/4 + 255)/256), 256, 0, stream>>>(
        (const float4*)past, (float4*)present);

    // 3) flash attention -> merged
    attn_kernel<<<dim3(S_/64, B_*H_), 256, 0, stream>>>(q_ws, present, merged);

    // 4) output projection
    gemm_kernel<1, 1024><<<dim3(8, 32), 256, 0, stream>>>(
        merged, w_proj, b_proj, nullptr, nullptr, out);
}

// Round 2
// 775.755 us; speedup vs baseline: 2.3293x; 2.3293x over previous
//
#include <hip/hip_runtime.h>
#include <hip/hip_bf16.h>

// Problem constants
#define B_ 2
#define S_ 2048
#define D_ 1024
#define H_ 16
#define P_ 2048
#define T_ 4096   // P_ + S_
#define DEPTH_ 64

typedef __bf16 bf16x8 __attribute__((ext_vector_type(8)));
typedef float  f32x4  __attribute__((ext_vector_type(4)));
typedef short  short8_t __attribute__((ext_vector_type(8)));
typedef unsigned short ushort_t;

// f32 -> bf16 round-to-nearest-even (values here are well-behaved, no NaN path)
__device__ __forceinline__ ushort_t f2bf(float f) {
    union { float f; unsigned u; } v; v.f = f;
    return (ushort_t)((v.u + 0x7fffu + ((v.u >> 16) & 1u)) >> 16);
}

// =====================================================================
// GEMM: C[4096, NCOLS] = A[4096,1024] @ W[1024,NCOLS] + bias  (fp32)
// 128x128 tile, K-step 16, 256 threads, 8x8 micro-tile per thread.
// MODE 0: QKV epilogue (scatter q -> ws, k/v -> present)
// MODE 1: plain epilogue (output projection)
// =====================================================================
template<int MODE, int NCOLS>
__global__ __launch_bounds__(256)
void gemm_kernel(const float* __restrict__ A, const float* __restrict__ W,
                 const float* __restrict__ bias,
                 float* __restrict__ out_q, float* __restrict__ out_present,
                 float* __restrict__ out_plain)
{
    __shared__ float As[16][132];   // [k][m], padded
    __shared__ float Bs[16][132];   // [k][n], padded

    const int tid  = threadIdx.x;
    const int ty   = tid >> 4;
    const int tx   = tid & 15;
    const int row0 = blockIdx.y * 128;
    const int col0 = blockIdx.x * 128;

    float acc[8][8];
    #pragma unroll
    for (int i = 0; i < 8; ++i)
        #pragma unroll
        for (int j = 0; j < 8; ++j) acc[i][j] = 0.f;

    for (int k0 = 0; k0 < 1024; k0 += 16) {
        #pragma unroll
        for (int rep = 0; rep < 2; ++rep) {
            const int idx = rep * 256 + tid;        // 0..511
            const int r  = idx >> 2, c  = idx & 3;
            float4 av = *(const float4*)&A[(size_t)(row0 + r) * 1024 + k0 + c * 4];
            As[c*4+0][r] = av.x; As[c*4+1][r] = av.y;
            As[c*4+2][r] = av.z; As[c*4+3][r] = av.w;
            const int kk = idx >> 5, cc = idx & 31;
            float4 bv = *(const float4*)&W[(size_t)(k0 + kk) * NCOLS + col0 + cc * 4];
            *(float4*)&Bs[kk][cc*4] = bv;
        }
        __syncthreads();

        #pragma unroll
        for (int kk = 0; kk < 16; ++kk) {
            float4 a0 = *(const float4*)&As[kk][ty*8];
            float4 a1 = *(const float4*)&As[kk][ty*8+4];
            float4 b0 = *(const float4*)&Bs[kk][tx*8];
            float4 b1 = *(const float4*)&Bs[kk][tx*8+4];
            float a[8]  = {a0.x,a0.y,a0.z,a0.w,a1.x,a1.y,a1.z,a1.w};
            float bb[8] = {b0.x,b0.y,b0.z,b0.w,b1.x,b1.y,b1.z,b1.w};
            #pragma unroll
            for (int i = 0; i < 8; ++i)
                #pragma unroll
                for (int j = 0; j < 8; ++j)
                    acc[i][j] = fmaf(a[i], bb[j], acc[i][j]);
        }
        __syncthreads();
    }

    #pragma unroll
    for (int i = 0; i < 8; ++i) {
        const int rm = row0 + ty * 8 + i;
        const int b  = rm >> 11;
        const int s  = rm & 2047;
        #pragma unroll
        for (int jg = 0; jg < 2; ++jg) {
            const int e0 = col0 + tx * 8 + jg * 4;
            float4 v;
            v.x = acc[i][jg*4+0] + bias[e0+0];
            v.y = acc[i][jg*4+1] + bias[e0+1];
            v.z = acc[i][jg*4+2] + bias[e0+2];
            v.w = acc[i][jg*4+3] + bias[e0+3];
            if (MODE == 0) {
                const int which = e0 >> 10;      // 0=q 1=k 2=v
                const int f = e0 & 1023;
                const int h = f >> 6, d = f & 63;
                if (which == 0) {
                    *(float4*)&out_q[(size_t)(((b*16 + h) * 2048 + s) << 6) + d] = v;
                } else {
                    const int kv = which - 1;
                    *(float4*)&out_present[((((size_t)(b*2 + kv)*16 + h) * 4096 + 2048 + s) << 6) + d] = v;
                }
            } else {
                *(float4*)&out_plain[(size_t)rm * 1024 + e0] = v;
            }
        }
    }
}

// =====================================================================
// past_layer [B,2,H,P,64] -> present[b,kv,h,0:P,:]
// =====================================================================
__global__ __launch_bounds__(256)
void copy_past_kernel(const float4* __restrict__ past, float4* __restrict__ present4)
{
    const int idx = blockIdx.x * 256 + threadIdx.x;
    if (idx >= (B_*2*H_*P_*DEPTH_)/4) return;
    const int c = idx >> 15;
    const int r = idx & 32767;
    present4[(size_t)c * (T_*DEPTH_/4) + r] = past[idx];
}

// =====================================================================
// Flash attention, bf16 MFMA (16x16x32).
// Block = 256 thr = 4 waves; each wave owns 16 q rows; q-block = 64 rows
// of one (b,h). K/V tiles of 64 keys staged LDS (fp32->bf16 in staging).
//   QK^T: A = Q (regs), B = K (LDS [key][d], pad 72)   -> S row=q, col=key
//   softmax: per-lane 4 rows, 16-lane __shfl_xor reduce
//   PV:   A = P (per-wave LDS re-layout), B = V^T (LDS [d][key], pad 72)
// Fragment layouts per verified m89/m91 mapping.
// =====================================================================
__global__ __launch_bounds__(256)
void attn_mfma_kernel(const float* __restrict__ qin,      // [B,H,S,64] f32
                      const float* __restrict__ present,  // [B,2,H,T,64] f32
                      float* __restrict__ merged)         // [B,S,D] f32
{
    __shared__ __attribute__((aligned(16))) ushort_t Ks[64][72];     // K [key][d]
    __shared__ __attribute__((aligned(16))) ushort_t Vt[64][72];     // V^T [d][key]
    __shared__ __attribute__((aligned(16))) ushort_t Ps[4][16][72];  // per-wave P [q][key]

    const int tid  = threadIdx.x;
    const int w    = tid >> 6;       // wave 0..3
    const int lane = tid & 63;
    const int g    = lane >> 4;      // 16-lane group 0..3
    const int ln   = lane & 15;

    // schedule long blocks (large q0 -> more KV tiles) first
    const int q0 = (gridDim.x - 1 - (int)blockIdx.x) * 64;
    const int bh = blockIdx.y;
    const int b  = bh >> 4, h = bh & 15;

    const float* Kb = present + ((size_t)(b*2 + 0)*16 + h) * (size_t)(T_*DEPTH_);
    const float* Vb = present + ((size_t)(b*2 + 1)*16 + h) * (size_t)(T_*DEPTH_);

    // Q A-frags: lane holds row q = ln, k = d = dh*32 + g*8 .. +7
    bf16x8 qf[2];
    {
        const float* Qr = qin + ((size_t)bh * S_ + q0 + w*16 + ln) * 64;
        #pragma unroll
        for (int dh = 0; dh < 2; ++dh) {
            const float* p = Qr + dh*32 + g*8;
            float4 x0 = *(const float4*)p;
            float4 x1 = *(const float4*)(p + 4);
            short8_t sv8;
            sv8[0]=f2bf(x0.x); sv8[1]=f2bf(x0.y); sv8[2]=f2bf(x0.z); sv8[3]=f2bf(x0.w);
            sv8[4]=f2bf(x1.x); sv8[5]=f2bf(x1.y); sv8[6]=f2bf(x1.z); sv8[7]=f2bf(x1.w);
            qf[dh] = __builtin_bit_cast(bf16x8, sv8);
        }
    }

    f32x4 o[4];                      // O accum: [d-subtile]; comps = 4 q-rows
    float m_r[4], l_r[4];
    #pragma unroll
    for (int r = 0; r < 4; ++r) {
        m_r[r] = -3.0e38f; l_r[r] = 0.f;
    }
    #pragma unroll
    for (int d = 0; d < 4; ++d) o[d] = (f32x4){0.f, 0.f, 0.f, 0.f};

    const int nt = q0 / 64 + 33;     // last tile = diagonal
    for (int t = 0; t < nt; ++t) {
        const int t0 = t * 64;
        // ---- stage K [key][d] and V^T [d][key], fp32 -> bf16 ----
        #pragma unroll
        for (int rep = 0; rep < 4; ++rep) {
            const int idx = rep * 256 + tid;          // 0..1023
            const int kr = idx >> 4, dgk = idx & 15;  // K: coalesced rows
            float4 kv = *(const float4*)&Kb[(size_t)(t0 + kr) * 64 + dgk * 4];
            unsigned klo = (unsigned)f2bf(kv.x) | ((unsigned)f2bf(kv.y) << 16);
            unsigned khi = (unsigned)f2bf(kv.z) | ((unsigned)f2bf(kv.w) << 16);
            *(unsigned*)&Ks[kr][dgk*4]     = klo;
            *(unsigned*)&Ks[kr][dgk*4 + 2] = khi;
            const int dgv = idx >> 6, vr = idx & 63;  // V: conflict-free transpose write
            float4 vv = *(const float4*)&Vb[(size_t)(t0 + vr) * 64 + dgv * 4];
            Vt[dgv*4+0][vr] = f2bf(vv.x);
            Vt[dgv*4+1][vr] = f2bf(vv.y);
            Vt[dgv*4+2][vr] = f2bf(vv.z);
            Vt[dgv*4+3][vr] = f2bf(vv.w);
        }
        __syncthreads();

        // ---- QK^T: s[js] covers keys js*16..+15 for this wave's 16 q rows ----
        f32x4 s[4];
        #pragma unroll
        for (int js = 0; js < 4; ++js) {
            s[js] = (f32x4){0.f, 0.f, 0.f, 0.f};
            const ushort_t* kp = &Ks[js*16 + ln][g*8];
            bf16x8 b0 = __builtin_bit_cast(bf16x8, *(const short8_t*)kp);
            bf16x8 b1 = __builtin_bit_cast(bf16x8, *(const short8_t*)(kp + 32));
            s[js] = __builtin_amdgcn_mfma_f32_16x16x32_bf16(qf[0], b0, s[js], 0, 0, 0);
            s[js] = __builtin_amdgcn_mfma_f32_16x16x32_bf16(qf[1], b1, s[js], 0, 0, 0);
        }

        // ---- scale + causal mask (diag tile only) + online softmax ----
        const bool diag = (t == nt - 1);
        #pragma unroll
        for (int r = 0; r < 4; ++r) {
            float sv[4];
            #pragma unroll
            for (int js = 0; js < 4; ++js) {
                float v = s[js][r] * 0.125f;    // 1/sqrt(64)
                // abs key = t0 + js*16 + ln; abs q pos = P_ + q0 + w*16 + g*4 + r
                if (diag && (js*16 + ln > w*16 + g*4 + r)) v = -1e30f;
                sv[js] = v;
            }
            float mx = fmaxf(fmaxf(sv[0], sv[1]), fmaxf(sv[2], sv[3]));
            mx = fmaxf(mx, __shfl_xor(mx, 1));
            mx = fmaxf(mx, __shfl_xor(mx, 2));
            mx = fmaxf(mx, __shfl_xor(mx, 4));
            mx = fmaxf(mx, __shfl_xor(mx, 8));
            const float mnew = fmaxf(m_r[r], mx);
            const float corr = __expf(m_r[r] - mnew);
            m_r[r] = mnew;
            float rs = 0.f;
            #pragma unroll
            for (int js = 0; js < 4; ++js) {
                const float p = __expf(sv[js] - mnew);
                rs += p;
                Ps[w][g*4 + r][js*16 + ln] = f2bf(p);
            }
            rs += __shfl_xor(rs, 1);
            rs += __shfl_xor(rs, 2);
            rs += __shfl_xor(rs, 4);
            rs += __shfl_xor(rs, 8);
            l_r[r] = l_r[r] * corr + rs;
            #pragma unroll
            for (int d = 0; d < 4; ++d) o[d][r] *= corr;
        }

        // ---- PV: A = P (wave-private LDS, no barrier needed), B = V^T ----
        #pragma unroll
        for (int ks = 0; ks < 2; ++ks) {
            bf16x8 a = __builtin_bit_cast(bf16x8,
                         *(const short8_t*)&Ps[w][ln][ks*32 + g*8]);
            #pragma unroll
            for (int d = 0; d < 4; ++d) {
                bf16x8 vb = __builtin_bit_cast(bf16x8,
                              *(const short8_t*)&Vt[d*16 + ln][ks*32 + g*8]);
                o[d] = __builtin_amdgcn_mfma_f32_16x16x32_bf16(a, vb, o[d], 0, 0, 0);
            }
        }
        __syncthreads();   // Ks/Vt reuse next tile
    }

    // ---- epilogue: merged[b, q, h*64 + d] = O / l ----
    #pragma unroll
    for (int r = 0; r < 4; ++r) {
        const float inv = 1.f / l_r[r];
        const int row = q0 + w*16 + g*4 + r;
        float* outp = &merged[((size_t)b * S_ + row) * D_ + h*64 + ln];
        #pragma unroll
        for (int d = 0; d < 4; ++d)
            outp[d*16] = o[d][r] * inv;
    }
}

// =====================================================================
extern "C" void kernel_launch(void* const* d_in, const int* in_sizes, int n_in,
                              void* d_out, int out_size, void* d_ws, size_t ws_size,
                              hipStream_t stream)
{
    const float* x      = (const float*)d_in[0];
    // d_in[1] = mask: causal structure computed analytically, never read
    const float* past   = (const float*)d_in[2];
    const float* w_attn = (const float*)d_in[3];
    const float* b_attn = (const float*)d_in[4];
    const float* w_proj = (const float*)d_in[5];
    const float* b_proj = (const float*)d_in[6];

    float* out     = (float*)d_out;                    // [B,S,D]
    float* present = out + (size_t)B_ * S_ * D_;       // [B,2,H,T,64]
    float* q_ws    = (float*)d_ws;                     // [B,H,S,64]
    float* merged  = q_ws + (size_t)B_ * H_ * S_ * DEPTH_;  // [B,S,D]

    // 1) QKV projection; scatter q->ws, k/v->present (new rows)
    gemm_kernel<0, 3072><<<dim3(24, 32), 256, 0, stream>>>(
        x, w_attn, b_attn, q_ws, present, nullptr);

    // 2) past -> present (rows 0..P-1)
    copy_past_kernel<<<dim3((B_*2*H_*P_*DEPTH_/4 + 255)/256), 256, 0, stream>>>(
        (const float4*)past, (float4*)present);

    // 3) flash attention (bf16 MFMA) -> merged
    attn_mfma_kernel<<<dim3(S_/64, B_*H_), 256, 0, stream>>>(q_ws, present, merged);

    // 4) output projection
    gemm_kernel<1, 1024><<<dim3(8, 32), 256, 0, stream>>>(
        merged, w_proj, b_proj, nullptr, nullptr, out);
}

// Round 3
// 419.121 us; speedup vs baseline: 4.3113x; 1.8509x over previous
//
#include <hip/hip_runtime.h>
#include <hip/hip_bf16.h>

// Problem constants
#define B_ 2
#define S_ 2048
#define D_ 1024
#define H_ 16
#define P_ 2048
#define T_ 4096   // P_ + S_
#define DEPTH_ 64

typedef __bf16 bf16x8 __attribute__((ext_vector_type(8)));
typedef float  f32x4  __attribute__((ext_vector_type(4)));
typedef short  short8_t __attribute__((ext_vector_type(8)));
typedef unsigned short ushort_t;
typedef unsigned short ushort4_t __attribute__((ext_vector_type(4)));

// f32 -> bf16 round-to-nearest-even
__device__ __forceinline__ ushort_t f2bf(float f) {
    union { float f; unsigned u; } v; v.f = f;
    return (ushort_t)((v.u + 0x7fffu + ((v.u >> 16) & 1u)) >> 16);
}

__device__ __forceinline__ void gload16(const void* g, void* l) {
    __builtin_amdgcn_global_load_lds(
        (const __attribute__((address_space(1))) unsigned int*)g,
        (__attribute__((address_space(3))) unsigned int*)l, 16, 0, 0);
}

// =====================================================================
// x [4096][1024] f32 -> bf16 (row-major, K-contiguous A operand)
// =====================================================================
__global__ __launch_bounds__(256)
void convert_bf16_kernel(const float4* __restrict__ in, ushort4_t* __restrict__ out, int n4)
{
    for (int i = blockIdx.x * 256 + threadIdx.x; i < n4; i += gridDim.x * 256) {
        float4 v = in[i];
        ushort4_t o;
        o[0] = f2bf(v.x); o[1] = f2bf(v.y); o[2] = f2bf(v.z); o[3] = f2bf(v.w);
        out[i] = o;
    }
}

// =====================================================================
// w [K=1024][N] f32 -> wt [N][1024] bf16 (transposed, B^T operand)
// 64x64 tile via LDS.
// =====================================================================
__global__ __launch_bounds__(256)
void transpose_conv_kernel(const float* __restrict__ w, ushort_t* __restrict__ wt, int N)
{
    __shared__ float t[64][65];
    const int tid = threadIdx.x;
    const int k0 = blockIdx.y * 64, n0 = blockIdx.x * 64;
    #pragma unroll
    for (int rep = 0; rep < 4; ++rep) {
        const int idx = rep * 256 + tid;
        const int r = idx >> 4, c = idx & 15;
        float4 v = *(const float4*)&w[(size_t)(k0 + r) * N + n0 + c * 4];
        t[r][c*4+0] = v.x; t[r][c*4+1] = v.y; t[r][c*4+2] = v.z; t[r][c*4+3] = v.w;
    }
    __syncthreads();
    #pragma unroll
    for (int rep = 0; rep < 4; ++rep) {
        const int idx = rep * 256 + tid;
        const int nl = idx >> 4, kg = idx & 15;
        ushort4_t o;
        o[0] = f2bf(t[kg*4+0][nl]); o[1] = f2bf(t[kg*4+1][nl]);
        o[2] = f2bf(t[kg*4+2][nl]); o[3] = f2bf(t[kg*4+3][nl]);
        *(ushort4_t*)&wt[(size_t)(n0 + nl) * 1024 + k0 + kg*4] = o;
    }
}

// =====================================================================
// bf16 MFMA GEMM (m97 structure): C[M][N] = A[M][1024] @ Bt[N][1024]^T + bias
// 128x128 tile, BK=32, 256 thr = 4 waves (2x2), 4x4 16x16x32 frags/wave.
// LDS XOR-swizzle byte ^= ((row>>1)&3)<<4 on both stage-source and read.
// MODE 0: QKV epilogue (q -> bf16 ws, k/v -> present f32)
// MODE 1: plain f32 epilogue (output projection)
// =====================================================================
template<int MODE>
__global__ __launch_bounds__(256)
void gemm_bf16_kernel(const ushort_t* __restrict__ A,   // [M][1024] bf16
                      const ushort_t* __restrict__ Bt,  // [N][1024] bf16
                      const float*  __restrict__ bias,
                      ushort_t* __restrict__ out_qb,    // MODE0: [B,H,S,64] bf16
                      float*  __restrict__ out_present, // MODE0: [B,2,H,T,64] f32
                      float*  __restrict__ out_plain)   // MODE1: [M][1024] f32
{
    __shared__ __attribute__((aligned(16))) ushort_t As[128*32];
    __shared__ __attribute__((aligned(16))) ushort_t Bs[128*32];

    const int tid  = threadIdx.x;
    const int w    = tid >> 6;
    const int lane = tid & 63;
    const int g    = lane >> 4;
    const int ln   = lane & 15;
    const int wr   = w >> 1, wc = w & 1;
    const int row0 = blockIdx.y * 128;
    const int col0 = blockIdx.x * 128;

    // staging constants: wave w, rep r covers LDS bytes (w*2+r)*1024 + lane*16
    int srow[2], sgl[2];
    #pragma unroll
    for (int r = 0; r < 2; ++r) {
        const int o = (w*2 + r) * 1024 + lane * 16;
        srow[r] = o >> 6;                       // logical row (64B rows)
        const int gp = (o >> 4) & 3;            // physical granule
        sgl[r] = gp ^ ((srow[r] >> 1) & 3);     // logical granule to fetch
    }

    f32x4 acc[4][4];
    #pragma unroll
    for (int i = 0; i < 4; ++i)
        #pragma unroll
        for (int j = 0; j < 4; ++j)
            acc[i][j] = (f32x4){0.f, 0.f, 0.f, 0.f};

    for (int k0 = 0; k0 < 1024; k0 += 32) {
        #pragma unroll
        for (int r = 0; r < 2; ++r) {
            const int lb = (w*2 + r) * 512;    // LDS base in ushorts
            gload16(&A [(size_t)(row0 + srow[r]) * 1024 + k0 + sgl[r]*8], &As[lb]);
            gload16(&Bt[(size_t)(col0 + srow[r]) * 1024 + k0 + sgl[r]*8], &Bs[lb]);
        }
        __syncthreads();

        bf16x8 af[4], bfr[4];
        #pragma unroll
        for (int i = 0; i < 4; ++i) {
            const int ra = wr*64 + i*16 + ln;
            const int ga = g ^ ((ra >> 1) & 3);
            af[i] = __builtin_bit_cast(bf16x8, *(const short8_t*)&As[ra*32 + ga*8]);
            const int rb = wc*64 + i*16 + ln;
            const int gb = g ^ ((rb >> 1) & 3);
            bfr[i] = __builtin_bit_cast(bf16x8, *(const short8_t*)&Bs[rb*32 + gb*8]);
        }
        #pragma unroll
        for (int i = 0; i < 4; ++i)
            #pragma unroll
            for (int j = 0; j < 4; ++j)
                acc[i][j] = __builtin_amdgcn_mfma_f32_16x16x32_bf16(af[i], bfr[j], acc[i][j], 0, 0, 0);
        __syncthreads();
    }

    // epilogue: C row = row0+wr*64+i*16+g*4+j ; col = col0+wc*64+jn*16+ln
    #pragma unroll
    for (int i = 0; i < 4; ++i) {
        #pragma unroll
        for (int j = 0; j < 4; ++j) {
            const int rm = row0 + wr*64 + i*16 + g*4 + j;
            const int b  = rm >> 11;
            const int s  = rm & 2047;
            #pragma unroll
            for (int jn = 0; jn < 4; ++jn) {
                const int e = col0 + wc*64 + jn*16 + ln;
                const float v = acc[i][jn][j] + bias[e];
                if (MODE == 0) {
                    const int which = e >> 10;   // 0=q 1=k 2=v (uniform per jn)
                    const int f = e & 1023;
                    const int h = f >> 6, d = f & 63;
                    if (which == 0) {
                        out_qb[(size_t)(((b*16 + h) * 2048 + s) << 6) + d] = f2bf(v);
                    } else {
                        const int kv = which - 1;
                        out_present[((((size_t)(b*2 + kv)*16 + h) * 4096 + 2048 + s) << 6) + d] = v;
                    }
                } else {
                    out_plain[(size_t)rm * 1024 + e] = v;
                }
            }
        }
    }
}

// =====================================================================
// past_layer [B,2,H,P,64] -> present[b,kv,h,0:P,:]
// =====================================================================
__global__ __launch_bounds__(256)
void copy_past_kernel(const float4* __restrict__ past, float4* __restrict__ present4)
{
    const int idx = blockIdx.x * 256 + threadIdx.x;
    if (idx >= (B_*2*H_*P_*DEPTH_)/4) return;
    const int c = idx >> 15;
    const int r = idx & 32767;
    present4[(size_t)c * (T_*DEPTH_/4) + r] = past[idx];
}

// =====================================================================
// Flash attention, bf16 MFMA (16x16x32). Q input bf16; merged output bf16.
// =====================================================================
__global__ __launch_bounds__(256)
void attn_mfma_kernel(const ushort_t* __restrict__ qin,  // [B,H,S,64] bf16
                      const float* __restrict__ present, // [B,2,H,T,64] f32
                      ushort_t* __restrict__ merged)     // [B,S,D] bf16
{
    __shared__ __attribute__((aligned(16))) ushort_t Ks[64][72];     // K [key][d]
    __shared__ __attribute__((aligned(16))) ushort_t Vt[64][72];     // V^T [d][key]
    __shared__ __attribute__((aligned(16))) ushort_t Ps[4][16][72];  // per-wave P [q][key]

    const int tid  = threadIdx.x;
    const int w    = tid >> 6;
    const int lane = tid & 63;
    const int g    = lane >> 4;
    const int ln   = lane & 15;

    const int q0 = (gridDim.x - 1 - (int)blockIdx.x) * 64;
    const int bh = blockIdx.y;
    const int b  = bh >> 4, h = bh & 15;

    const float* Kb = present + ((size_t)(b*2 + 0)*16 + h) * (size_t)(T_*DEPTH_);
    const float* Vb = present + ((size_t)(b*2 + 1)*16 + h) * (size_t)(T_*DEPTH_);

    bf16x8 qf[2];
    {
        const ushort_t* Qr = qin + ((size_t)bh * S_ + q0 + w*16 + ln) * 64;
        #pragma unroll
        for (int dh = 0; dh < 2; ++dh)
            qf[dh] = __builtin_bit_cast(bf16x8, *(const short8_t*)(Qr + dh*32 + g*8));
    }

    f32x4 o[4];
    float m_r[4], l_r[4];
    #pragma unroll
    for (int r = 0; r < 4; ++r) { m_r[r] = -3.0e38f; l_r[r] = 0.f; }
    #pragma unroll
    for (int d = 0; d < 4; ++d) o[d] = (f32x4){0.f, 0.f, 0.f, 0.f};

    const int nt = q0 / 64 + 33;     // last tile = diagonal
    for (int t = 0; t < nt; ++t) {
        const int t0 = t * 64;
        #pragma unroll
        for (int rep = 0; rep < 4; ++rep) {
            const int idx = rep * 256 + tid;
            const int kr = idx >> 4, dgk = idx & 15;
            float4 kv = *(const float4*)&Kb[(size_t)(t0 + kr) * 64 + dgk * 4];
            unsigned klo = (unsigned)f2bf(kv.x) | ((unsigned)f2bf(kv.y) << 16);
            unsigned khi = (unsigned)f2bf(kv.z) | ((unsigned)f2bf(kv.w) << 16);
            *(unsigned*)&Ks[kr][dgk*4]     = klo;
            *(unsigned*)&Ks[kr][dgk*4 + 2] = khi;
            const int dgv = idx >> 6, vr = idx & 63;
            float4 vv = *(const float4*)&Vb[(size_t)(t0 + vr) * 64 + dgv * 4];
            Vt[dgv*4+0][vr] = f2bf(vv.x);
            Vt[dgv*4+1][vr] = f2bf(vv.y);
            Vt[dgv*4+2][vr] = f2bf(vv.z);
            Vt[dgv*4+3][vr] = f2bf(vv.w);
        }
        __syncthreads();

        f32x4 s[4];
        #pragma unroll
        for (int js = 0; js < 4; ++js) {
            s[js] = (f32x4){0.f, 0.f, 0.f, 0.f};
            const ushort_t* kp = &Ks[js*16 + ln][g*8];
            bf16x8 b0 = __builtin_bit_cast(bf16x8, *(const short8_t*)kp);
            bf16x8 b1 = __builtin_bit_cast(bf16x8, *(const short8_t*)(kp + 32));
            s[js] = __builtin_amdgcn_mfma_f32_16x16x32_bf16(qf[0], b0, s[js], 0, 0, 0);
            s[js] = __builtin_amdgcn_mfma_f32_16x16x32_bf16(qf[1], b1, s[js], 0, 0, 0);
        }

        const bool diag = (t == nt - 1);
        #pragma unroll
        for (int r = 0; r < 4; ++r) {
            float sv[4];
            #pragma unroll
            for (int js = 0; js < 4; ++js) {
                float v = s[js][r] * 0.125f;
                if (diag && (js*16 + ln > w*16 + g*4 + r)) v = -1e30f;
                sv[js] = v;
            }
            float mx = fmaxf(fmaxf(sv[0], sv[1]), fmaxf(sv[2], sv[3]));
            mx = fmaxf(mx, __shfl_xor(mx, 1));
            mx = fmaxf(mx, __shfl_xor(mx, 2));
            mx = fmaxf(mx, __shfl_xor(mx, 4));
            mx = fmaxf(mx, __shfl_xor(mx, 8));
            const float mnew = fmaxf(m_r[r], mx);
            const float corr = __expf(m_r[r] - mnew);
            m_r[r] = mnew;
            float rs = 0.f;
            #pragma unroll
            for (int js = 0; js < 4; ++js) {
                const float p = __expf(sv[js] - mnew);
                rs += p;
                Ps[w][g*4 + r][js*16 + ln] = f2bf(p);
            }
            rs += __shfl_xor(rs, 1);
            rs += __shfl_xor(rs, 2);
            rs += __shfl_xor(rs, 4);
            rs += __shfl_xor(rs, 8);
            l_r[r] = l_r[r] * corr + rs;
            #pragma unroll
            for (int d = 0; d < 4; ++d) o[d][r] *= corr;
        }

        #pragma unroll
        for (int ks = 0; ks < 2; ++ks) {
            bf16x8 a = __builtin_bit_cast(bf16x8,
                         *(const short8_t*)&Ps[w][ln][ks*32 + g*8]);
            #pragma unroll
            for (int d = 0; d < 4; ++d) {
                bf16x8 vb = __builtin_bit_cast(bf16x8,
                              *(const short8_t*)&Vt[d*16 + ln][ks*32 + g*8]);
                o[d] = __builtin_amdgcn_mfma_f32_16x16x32_bf16(a, vb, o[d], 0, 0, 0);
            }
        }
        __syncthreads();
    }

    #pragma unroll
    for (int r = 0; r < 4; ++r) {
        const float inv = 1.f / l_r[r];
        const int row = q0 + w*16 + g*4 + r;
        ushort_t* outp = &merged[((size_t)b * S_ + row) * D_ + h*64 + ln];
        #pragma unroll
        for (int d = 0; d < 4; ++d)
            outp[d*16] = f2bf(o[d][r] * inv);
    }
}

// =====================================================================
extern "C" void kernel_launch(void* const* d_in, const int* in_sizes, int n_in,
                              void* d_out, int out_size, void* d_ws, size_t ws_size,
                              hipStream_t stream)
{
    const float* x      = (const float*)d_in[0];
    // d_in[1] = mask: causal structure computed analytically, never read
    const float* past   = (const float*)d_in[2];
    const float* w_attn = (const float*)d_in[3];
    const float* b_attn = (const float*)d_in[4];
    const float* w_proj = (const float*)d_in[5];
    const float* b_proj = (const float*)d_in[6];

    float* out     = (float*)d_out;                    // [B,S,D]
    float* present = out + (size_t)B_ * S_ * D_;       // [B,2,H,T,64]

    // ws layout (ushorts): 32 MB total
    ushort_t* xb      = (ushort_t*)d_ws;               // [4096][1024]   8 MB
    ushort_t* watb    = xb + 4194304;                  // [3072][1024]   6 MB
    ushort_t* wptb    = watb + 3145728;                // [1024][1024]   2 MB
    ushort_t* q_ws    = wptb + 1048576;                // [B,H,S,64]     8 MB
    ushort_t* mergedb = q_ws + 4194304;                // [4096][1024]   8 MB

    // 0) prep: convert x, transpose-convert weights
    convert_bf16_kernel<<<2048, 256, 0, stream>>>(
        (const float4*)x, (ushort4_t*)xb, (B_*S_*D_)/4);
    transpose_conv_kernel<<<dim3(48, 16), 256, 0, stream>>>(w_attn, watb, 3072);
    transpose_conv_kernel<<<dim3(16, 16), 256, 0, stream>>>(w_proj, wptb, 1024);

    // 1) QKV projection (bf16 MFMA); q -> bf16 ws, k/v -> present f32
    gemm_bf16_kernel<0><<<dim3(24, 32), 256, 0, stream>>>(
        xb, watb, b_attn, q_ws, present, nullptr);

    // 2) past -> present (rows 0..P-1)
    copy_past_kernel<<<dim3((B_*2*H_*P_*DEPTH_/4 + 255)/256), 256, 0, stream>>>(
        (const float4*)past, (float4*)present);

    // 3) flash attention (bf16 MFMA) -> merged bf16
    attn_mfma_kernel<<<dim3(S_/64, B_*H_), 256, 0, stream>>>(q_ws, present, mergedb);

    // 4) output projection (bf16 MFMA)
    gemm_bf16_kernel<1><<<dim3(8, 32), 256, 0, stream>>>(
        mergedb, wptb, b_proj, nullptr, nullptr, out);
}